// Round 14
// baseline (144.994 us; speedup 1.0000x reference)
//
#include <hip/hip_runtime.h>
#include <hip/hip_bf16.h>
#include <math.h>

// Problem constants: B=16, L=4096, N=512, D=256
#define BB 16
#define LL 4096
#define NN 512
#define DD 256

typedef __attribute__((ext_vector_type(8))) short  bf16x8; // MFMA A/B frag
typedef __attribute__((ext_vector_type(4))) float  f32x4;  // MFMA C/D frag
typedef __attribute__((ext_vector_type(4))) unsigned short u16x4;
typedef __attribute__((ext_vector_type(8))) unsigned short u16x8;

typedef __attribute__((address_space(1))) const void  gvoid_t;
typedef __attribute__((address_space(3))) void        lvoid_t;

#define GLL16(src, dst) __builtin_amdgcn_global_load_lds((gvoid_t*)(src), (lvoid_t*)(dst), 16, 0, 0)

__device__ __forceinline__ unsigned short f2bf(float x) {
    union { float f; unsigned u; } v; v.f = x;
    unsigned r = v.u + 0x7fffu + ((v.u >> 16) & 1u);   // RNE
    return (unsigned short)(r >> 16);
}
__device__ __forceinline__ float bfhi(unsigned u) { return __uint_as_float(u & 0xffff0000u); }
__device__ __forceinline__ float bflo(unsigned u) { return __uint_as_float(u << 16); }

// ---------------- prologue: P -> fragment-major bf16 images (R7-proven) ----
// Per (b, chunk c of 32 n), 16KB tiles. lane16 = g*16+lo.
//  pn (normalized): addr = ks*2048 + half*1024 + lane16*16 + j*2
//      = bf16( p_hat[n = c*32 + half*16 + lo][d = ks*32 + g*8 + j] )
//  pe (raw):        addr = df*1024 + lane16*16 + j*2
//      = bf16( p[n = c*32 + g*4 + (j&3) + 16*(j>>2)][d = df*16 + lo] )
__global__ __launch_bounds__(256) void cda_prep(
    const float* __restrict__ P, char* __restrict__ pnI, char* __restrict__ peI)
{
    __shared__ __align__(16) char raw[16384];   // [32 nl][256 d] bf16, ^((nl&7)<<4)

    const int blk = blockIdx.x;
    const int b   = blk >> 4;
    const int c   = blk & 15;
    const int tid = threadIdx.x;
    const int nl  = tid >> 3;          // chunk-local profile row
    const int sub = tid & 7;           // d-block of 32

    const float* rowp = P + (((size_t)b * NN + c * 32 + nl) * DD + sub * 32);
    float4 v[8];
    #pragma unroll
    for (int k = 0; k < 8; ++k) v[k] = *(const float4*)(rowp + k * 4);

    float ss = 0.f;
    #pragma unroll
    for (int k = 0; k < 8; ++k)
        ss += v[k].x * v[k].x + v[k].y * v[k].y + v[k].z * v[k].z + v[k].w * v[k].w;
    ss += __shfl_xor(ss, 1); ss += __shfl_xor(ss, 2); ss += __shfl_xor(ss, 4);
    const float rinv = 1.0f / sqrtf(ss);

    const size_t tile = ((size_t)b * 16 + c) * 16384;

    // pn: normalized, thread covers ks=sub, all g
    #pragma unroll
    for (int g = 0; g < 4; ++g) {
        u16x8 h;
        #pragma unroll
        for (int j = 0; j < 8; ++j) {
            const int dl = g * 8 + j;                  // d-local 0..31
            const float f = ((const float*)&v[dl >> 2])[dl & 3];
            h[j] = f2bf(f * rinv);
        }
        *(u16x8*)(pnI + tile + sub * 2048 + (nl >> 4) * 1024 + (g * 16 + (nl & 15)) * 16) = h;
    }

    // raw bf16 to LDS for the transpose
    #pragma unroll
    for (int g = 0; g < 4; ++g) {
        u16x8 h;
        #pragma unroll
        for (int j = 0; j < 8; ++j) {
            const int dl = g * 8 + j;
            h[j] = f2bf(((const float*)&v[dl >> 2])[dl & 3]);
        }
        *(u16x8*)(raw + ((nl * 512 + sub * 64 + g * 16) ^ ((nl & 7) << 4))) = h;
    }
    __syncthreads();

    // pe: thread owns d' = tid, gathers the 32 n-values, writes k-permuted frags
    unsigned short arr[32];
    #pragma unroll
    for (int r = 0; r < 32; ++r)
        arr[r] = *(const unsigned short*)(raw + ((r * 512 + tid * 2) ^ ((r & 7) << 4)));
    #pragma unroll
    for (int g = 0; g < 4; ++g) {
        u16x8 h;
        #pragma unroll
        for (int j = 0; j < 8; ++j)
            h[j] = arr[g * 4 + (j & 3) + 16 * (j >> 2)];
        *(u16x8*)(peI + tile + (tid >> 4) * 1024 + (g * 16 + (tid & 15)) * 16) = h;
    }
}

// ---------------- main kernel ---------------------------------------------
// FUSED single-pass, sync-paranoid: 1024 blocks x 256 threads (4 waves),
// 64 L-rows/block.  Per chunk c: S(c) -> p=exp -> E += p.pe (E needs no sinv:
// normalization distributes).  ALL sync via plain __syncthreads() (full
// compiler-emitted vmcnt/lgkm drains) -- no hand-rolled waitcnt asm.
// 2 x 32KB double buffer (each = pn(c) [0,16K) | pe(c) [16K,32K)); chunk c+1
// issued right after the iter-c sync -> a full iteration of landing time.
// W stores = tail burst AFTER the epilogue sync (only consumer of sinv).
__global__ __launch_bounds__(256, 2) void cda_main(
    const float* __restrict__ X, const char* __restrict__ pnI,
    const char* __restrict__ peI, const int* __restrict__ lens,
    float* __restrict__ out)
{
    __shared__ __align__(16) char stg[65536];   // 2 x 32KB; X-stage / epilogue scratch

    const int id = blockIdx.x;
    const int b  = (id & 7) * 2 + (id >> 9);    // XCD-bijective: 2 batches per XCD
    const int l0 = ((id >> 3) & 63) * 64;

    const int tid  = threadIdx.x;
    const int w    = tid >> 6;
    const int lane = tid & 63;
    const int lo   = lane & 15;
    const int g    = lane >> 4;
    const int len  = lens[b];

    const float* Xb  = X + ((size_t)b * LL + l0) * DD;
    const char*  pnB = pnI + (size_t)b * 262144;
    const char*  peB = peI + (size_t)b * 262144;

    // ---- prime chunk 0 -> buf0: pn0 [0,16K), pe0 [16K,32K) ----
    #pragma unroll
    for (int q = 0; q < 4; ++q)
        GLL16(pnB + q * 4096 + tid * 16, stg + q * 4096 + tid * 16);
    #pragma unroll
    for (int q = 0; q < 4; ++q)
        GLL16(peB + q * 4096 + tid * 16, stg + 16384 + q * 4096 + tid * 16);

    // ---- stage RAW X bf16 into buf1 [32K,64K); own-row 1/||x|| ----
    float xinv = 0.f;
    #pragma unroll
    for (int rr = 0; rr < 16; ++rr) {
        const int row = w * 16 + rr;
        const float4 v = *(const float4*)(Xb + row * DD + lane * 4);
        float ss = v.x * v.x + v.y * v.y + v.z * v.z + v.w * v.w;
        #pragma unroll
        for (int off = 32; off > 0; off >>= 1) ss += __shfl_xor(ss, off);
        const float inv = 1.0f / sqrtf(ss);
        if (rr == lo) xinv = inv;              // row w*16+lo belongs to this thread
        u16x4 h; h.x = f2bf(v.x); h.y = f2bf(v.y); h.z = f2bf(v.z); h.w = f2bf(v.w);
        *(u16x4*)(stg + 32768 + ((row * 512 + lane * 8) ^ ((row & 7) << 4))) = h;
    }
    __syncthreads();                           // X staged (also drains chunk0 DMA)
    bf16x8 xf[8];                              // x[w*16+lo][ks*32+g*8+j]
    #pragma unroll
    for (int ks = 0; ks < 8; ++ks)
        xf[ks] = *(const bf16x8*)(stg + 32768 +
            (((w * 16 + lo) * 512 + ks * 64 + g * 16) ^ ((lo & 7) << 4)));
    __syncthreads();                           // xf read everywhere; buf1 free

    // ---- prime chunk 1 -> buf1 ----
    #pragma unroll
    for (int q = 0; q < 4; ++q)
        GLL16(pnB + 16384 + q * 4096 + tid * 16, stg + 32768 + q * 4096 + tid * 16);
    #pragma unroll
    for (int q = 0; q < 4; ++q)
        GLL16(peB + 16384 + q * 4096 + tid * 16, stg + 49152 + q * 4096 + tid * 16);

    unsigned pm[16][4];
    float ssum = 0.f;
    f32x4 e[16];
    #pragma unroll
    for (int i = 0; i < 16; ++i) e[i] = (f32x4){0.f, 0.f, 0.f, 0.f};

    // ================= fused S+E loop (16 full syncs) =================
    #pragma unroll
    for (int c = 0; c < 16; ++c) {
        __syncthreads();   // full drain: chunk c resident in buf(c&1); all
                           // iter c-1 readers of buf((c+1)&1) retired.
        if (c >= 1 && c < 15) {                // issue chunk c+1 -> buf((c+1)&1)
            const char* srcn = pnB + (size_t)(c + 1) * 16384;
            const char* srce = peB + (size_t)(c + 1) * 16384;
            char* dst = stg + ((c + 1) & 1) * 32768;
            #pragma unroll
            for (int q = 0; q < 4; ++q)
                GLL16(srcn + q * 4096 + tid * 16, dst + q * 4096 + tid * 16);
            #pragma unroll
            for (int q = 0; q < 4; ++q)
                GLL16(srce + q * 4096 + tid * 16, dst + 16384 + q * 4096 + tid * 16);
        }
        const char* pnL = stg + (c & 1) * 32768;

        // ---- S(c): 8 k-steps, contiguous 1KB wave reads ----
        f32x4 a0 = (f32x4){0.f, 0.f, 0.f, 0.f};
        f32x4 a1 = (f32x4){0.f, 0.f, 0.f, 0.f};
        #pragma unroll
        for (int ks = 0; ks < 8; ++ks) {
            const bf16x8 f0 = *(const bf16x8*)(pnL + ks * 2048 + lane * 16);
            const bf16x8 f1 = *(const bf16x8*)(pnL + ks * 2048 + 1024 + lane * 16);
            a0 = __builtin_amdgcn_mfma_f32_16x16x32_bf16(f0, xf[ks], a0, 0, 0, 0);
            a1 = __builtin_amdgcn_mfma_f32_16x16x32_bf16(f1, xf[ks], a1, 0, 0, 0);
        }
        // ---- p = exp(sim) (|sim|<=1 -> no max pass), mask, pack ----
        unsigned short pw[8];
        #pragma unroll
        for (int r = 0; r < 4; ++r) {
            const int n0 = c * 32 + g * 4 + r;
            const float p0 = (n0 < len) ? __expf(a0[r] * xinv) : 0.f;
            ssum += p0; pw[r] = f2bf(p0);
            const float p1 = (n0 + 16 < len) ? __expf(a1[r] * xinv) : 0.f;
            ssum += p1; pw[4 + r] = f2bf(p1);
        }
        pm[c][0] = (unsigned)pw[0] | ((unsigned)pw[1] << 16);
        pm[c][1] = (unsigned)pw[2] | ((unsigned)pw[3] << 16);
        pm[c][2] = (unsigned)pw[4] | ((unsigned)pw[5] << 16);
        pm[c][3] = (unsigned)pw[6] | ((unsigned)pw[7] << 16);

        // ---- E += p(c) . pe(c)  (unnormalized; sinv applied in epilogue) ----
        union { unsigned u[4]; bf16x8 v; } pf;
        pf.u[0] = pm[c][0]; pf.u[1] = pm[c][1];
        pf.u[2] = pm[c][2]; pf.u[3] = pm[c][3];
        const char* peL = pnL + 16384;
        #pragma unroll
        for (int df = 0; df < 16; ++df) {      // contiguous 1KB wave reads
            const bf16x8 bf = *(const bf16x8*)(peL + df * 1024 + lane * 16);
            e[df] = __builtin_amdgcn_mfma_f32_16x16x32_bf16(pf.v, bf, e[df], 0, 0, 0);
        }
    }

    // ---- row sum (row w*16+lo lives on lanes lo, lo+16, lo+32, lo+48) ----
    ssum += __shfl_xor(ssum, 16);
    ssum += __shfl_xor(ssum, 32);
    const float sinv = 1.0f / ssum;

    __syncthreads();                           // all iter-15 readers done -> scratch ok

    // ---- E epilogue: per-wave transpose via own 16KB slab, float4 stores ----
    float t4[4];
    #pragma unroll
    for (int r = 0; r < 4; ++r) t4[r] = __shfl(sinv, g * 4 + r);
    char* scr = stg + w * 16384;               // stride 1056: writes 2-way, reads linear
    float* Eout = out + ((size_t)b * LL + l0 + w * 16) * DD;
    #pragma unroll
    for (int r = 0; r < 4; ++r) {
        #pragma unroll
        for (int df = 0; df < 16; ++df)
            *(float*)(scr + g * 1056 + df * 64 + lo * 4) = e[df][r] * t4[r];
        #pragma unroll
        for (int it = 0; it < 4; ++it) {
            const float4 t = *(const float4*)(scr + it * 1056 + lane * 16);
            *(float4*)(Eout + (size_t)(it * 4 + r) * DD + lane * 4) = t;
        }
    }

    // ---- W tail burst: full 128B line per row across the wave ----
    float* Wrow = out + (size_t)BB * LL * DD
                + ((size_t)b * LL + l0 + w * 16 + lo) * (size_t)NN;
    #pragma unroll
    for (int c = 0; c < 16; ++c) {
        float4 v0, v1;
        v0.x = bflo(pm[c][0]) * sinv; v0.y = bfhi(pm[c][0]) * sinv;
        v0.z = bflo(pm[c][1]) * sinv; v0.w = bfhi(pm[c][1]) * sinv;
        v1.x = bflo(pm[c][2]) * sinv; v1.y = bfhi(pm[c][2]) * sinv;
        v1.z = bflo(pm[c][3]) * sinv; v1.w = bfhi(pm[c][3]) * sinv;
        *(float4*)(Wrow + c * 32 + g * 4)      = v0;
        *(float4*)(Wrow + c * 32 + 16 + g * 4) = v1;
    }
}

extern "C" void kernel_launch(void* const* d_in, const int* in_sizes, int n_in,
                              void* d_out, int out_size, void* d_ws, size_t ws_size,
                              hipStream_t stream) {
    const float* X    = (const float*)d_in[0];
    const float* P    = (const float*)d_in[1];
    const int*   lens = (const int*)d_in[2];
    float*       out  = (float*)d_out;

    // workspace: pnI (4MB) | peI (4MB)
    char* pnI = (char*)d_ws;
    char* peI = (char*)d_ws + 4194304;

    hipLaunchKernelGGL(cda_prep, dim3(BB * 16), dim3(256), 0, stream, P, pnI, peI);
    hipLaunchKernelGGL(cda_main, dim3(1024), dim3(256), 0, stream, X, pnI, peI, lens, out);
}

// Round 15
// 81.655 us; speedup vs baseline: 1.7757x; 1.7757x over previous
//
#include <hip/hip_runtime.h>
#include <hip/hip_bf16.h>
#include <math.h>

// Problem constants: B=16, L=4096, N=512, D=256
#define BB 16
#define LL 4096
#define NN 512
#define DD 256

typedef __attribute__((ext_vector_type(8))) short  bf16x8; // MFMA A/B frag
typedef __attribute__((ext_vector_type(4))) float  f32x4;  // MFMA C/D frag
typedef __attribute__((ext_vector_type(4))) unsigned short u16x4;
typedef __attribute__((ext_vector_type(8))) unsigned short u16x8;

typedef __attribute__((address_space(1))) const void  gvoid_t;
typedef __attribute__((address_space(3))) void        lvoid_t;

#define GLL16(src, dst) __builtin_amdgcn_global_load_lds((gvoid_t*)(src), (lvoid_t*)(dst), 16, 0, 0)

__device__ __forceinline__ unsigned short f2bf(float x) {
    union { float f; unsigned u; } v; v.f = x;
    unsigned r = v.u + 0x7fffu + ((v.u >> 16) & 1u);   // RNE
    return (unsigned short)(r >> 16);
}
__device__ __forceinline__ float bfhi(unsigned u) { return __uint_as_float(u & 0xffff0000u); }
__device__ __forceinline__ float bflo(unsigned u) { return __uint_as_float(u << 16); }

// ---------------- prologue: P -> fragment-major bf16 images ----------------
// Same output layout as the proven R7 prep, but 512 threads/block (2x waves,
// half the per-thread work -> latency-bound prep runs ~2x faster).
// Per (b, chunk c of 32 n), 16KB tiles:
//  pn element (n=nl, d): (d>>5)*2048 + (nl>>4)*1024 + (((d>>3)&3)*16+(nl&15))*16 + (d&7)*2
//  pe frag: df*1024 + (g*16+lo)*16 + j*2 = p[n = g*4+(j&3)+16*(j>>2)][d = df*16+lo]
__global__ __launch_bounds__(512) void cda_prep(
    const float* __restrict__ P, char* __restrict__ pnI, char* __restrict__ peI)
{
    __shared__ __align__(16) char raw[16384];   // [32 nl][256 d] bf16, ^((nl&7)<<4)

    const int blk = blockIdx.x;
    const int b   = blk >> 4;
    const int c   = blk & 15;
    const int t   = threadIdx.x;

    // ---- phase A: load 16 floats, row-norm over 16 lanes, pn + raw writes ----
    const int nl  = t >> 4;            // 0..31 chunk-local profile row
    const int sub = t & 15;            // 0..15 d-block of 16
    const float* rowp = P + (((size_t)b * NN + c * 32 + nl) * DD + sub * 16);
    float4 v[4];
    #pragma unroll
    for (int k = 0; k < 4; ++k) v[k] = *(const float4*)(rowp + k * 4);

    float ss = 0.f;
    #pragma unroll
    for (int k = 0; k < 4; ++k)
        ss += v[k].x * v[k].x + v[k].y * v[k].y + v[k].z * v[k].z + v[k].w * v[k].w;
    ss += __shfl_xor(ss, 1); ss += __shfl_xor(ss, 2);
    ss += __shfl_xor(ss, 4); ss += __shfl_xor(ss, 8);   // 16 row-lanes are consecutive
    const float rinv = 1.0f / sqrtf(ss);

    const size_t tile = ((size_t)b * 16 + c) * 16384;

    #pragma unroll
    for (int h2 = 0; h2 < 2; ++h2) {               // two 8-float halves
        const int d0 = sub * 16 + h2 * 8;
        const int ks = d0 >> 5;
        const int gg = (d0 >> 3) & 3;
        u16x8 hn, hr;
        #pragma unroll
        for (int j = 0; j < 8; ++j) {
            const float f = ((const float*)&v[h2 * 2 + (j >> 2)])[j & 3];
            hn[j] = f2bf(f * rinv);                // normalized (pn)
            hr[j] = f2bf(f);                       // raw (transpose staging)
        }
        *(u16x8*)(pnI + tile + ks * 2048 + (nl >> 4) * 1024
                  + (gg * 16 + (nl & 15)) * 16) = hn;
        *(u16x8*)(raw + ((nl * 512 + d0 * 2) ^ ((nl & 7) << 4))) = hr;
    }
    __syncthreads();

    // ---- phase B: pe transpose; thread owns column col, row-half rh ----
    const int col = t >> 1;            // 0..255 = d
    const int rh  = t & 1;             // 0: rows 0-15, 1: rows 16-31
    unsigned short arr[16];
    #pragma unroll
    for (int r = 0; r < 16; ++r)
        arr[r] = *(const unsigned short*)(raw +
            (((rh * 16 + r) * 512 + col * 2) ^ ((r & 7) << 4)));
    #pragma unroll
    for (int g = 0; g < 4; ++g) {
        u16x4 h;
        h.x = arr[g * 4 + 0]; h.y = arr[g * 4 + 1];
        h.z = arr[g * 4 + 2]; h.w = arr[g * 4 + 3];
        *(u16x4*)(peI + tile + (col >> 4) * 1024
                  + (g * 16 + (col & 15)) * 16 + rh * 8) = h;
    }
}

// ---------------- main kernel (R7, bit-identical: 82.0 us) -----------------
// 1024 blocks x 256 threads (4 waves), 64 L-rows/block (wave w: rows w*16..+15).
// 4x16KB staging ring (depth-3 prefetch, counted vmcnt, never drains to 0).
// S phase: chunks 0..15 from pn (S iters 13-15 pre-issue pe0-2).
// E phase: chunks 0..15 from pe, W float4 stores interleaved.
__global__ __launch_bounds__(256, 2) void cda_main(
    const float* __restrict__ X, const char* __restrict__ pnI,
    const char* __restrict__ peI, const int* __restrict__ lens,
    float* __restrict__ out)
{
    __shared__ __align__(16) char stg[65536];   // 4 x 16KB ring; epilogue scratch

    const int id = blockIdx.x;
    const int b  = (id & 7) * 2 + (id >> 9);    // XCD-bijective: 2 batches per XCD
    const int l0 = ((id >> 3) & 63) * 64;

    const int tid  = threadIdx.x;
    const int w    = tid >> 6;
    const int lane = tid & 63;
    const int lo   = lane & 15;
    const int g    = lane >> 4;
    const int len  = lens[b];

    const float* Xb  = X + ((size_t)b * LL + l0) * DD;
    const char*  pnB = pnI + (size_t)b * 262144;
    const char*  peB = peI + (size_t)b * 262144;

    // ---- prefetch chunk-0 pn into buf 0 ----
    #pragma unroll
    for (int q = 0; q < 4; ++q)
        GLL16(pnB + q * 4096 + tid * 16, stg + q * 4096 + tid * 16);

    // ---- stage RAW X bf16 into bufs 1-2 region [16K,48K); own-row 1/||x|| ----
    float xinv = 0.f;
    #pragma unroll
    for (int rr = 0; rr < 16; ++rr) {
        const int row = w * 16 + rr;
        const float4 v = *(const float4*)(Xb + row * DD + lane * 4);
        float ss = v.x * v.x + v.y * v.y + v.z * v.z + v.w * v.w;
        #pragma unroll
        for (int off = 32; off > 0; off >>= 1) ss += __shfl_xor(ss, off);
        const float inv = 1.0f / sqrtf(ss);
        if (rr == lo) xinv = inv;              // row w*16+lo belongs to this thread
        u16x4 h; h.x = f2bf(v.x); h.y = f2bf(v.y); h.z = f2bf(v.z); h.w = f2bf(v.w);
        *(u16x4*)(stg + 16384 + ((row * 512 + lane * 8) ^ ((row & 7) << 4))) = h;
    }
    __syncthreads();                           // X staged for all waves
    bf16x8 xf[8];                              // x[w*16+lo][ks*32+g*8+j]
    #pragma unroll
    for (int ks = 0; ks < 8; ++ks)
        xf[ks] = *(const bf16x8*)(stg + 16384 +
            (((w * 16 + lo) * 512 + ks * 64 + g * 16) ^ ((lo & 7) << 4)));
    __syncthreads();                           // xf read everywhere; bufs 1-3 free

    // ---- prime the ring: pn1 -> buf1, pn2 -> buf2 ----
    #pragma unroll
    for (int q = 0; q < 4; ++q)
        GLL16(pnB + 16384 + q * 4096 + tid * 16, stg + 16384 + q * 4096 + tid * 16);
    #pragma unroll
    for (int q = 0; q < 4; ++q)
        GLL16(pnB + 32768 + q * 4096 + tid * 16, stg + 32768 + q * 4096 + tid * 16);

    unsigned pm[16][4];
    float ssum = 0.f;

    // ================= S phase =================
    // Iter c: queue before wait = [pn(c) 4, pn(c+1) 4, pn(c+2) 4] (max 12).
    // vmcnt(8) completes pn(c); two chunks always in flight.
    #pragma unroll
    for (int c = 0; c < 16; ++c) {
        asm volatile("s_waitcnt vmcnt(8)" ::: "memory");
        __builtin_amdgcn_s_barrier();
        __builtin_amdgcn_sched_barrier(0);
        {   // issue chunk c+3 into buf (c+3)&3 (its old readers passed the barrier)
            const char* src = (c < 13) ? (pnB + (c + 3) * 16384)
                                       : (peB + (c - 13) * 16384);
            char* dst = stg + ((c + 3) & 3) * 16384;
            #pragma unroll
            for (int q = 0; q < 4; ++q)
                GLL16(src + q * 4096 + tid * 16, dst + q * 4096 + tid * 16);
        }
        const char* pnL = stg + (c & 3) * 16384;
        f32x4 a0 = (f32x4){0.f, 0.f, 0.f, 0.f};
        f32x4 a1 = (f32x4){0.f, 0.f, 0.f, 0.f};
        #pragma unroll
        for (int ks = 0; ks < 8; ++ks) {       // contiguous 1KB wave reads
            const bf16x8 f0 = *(const bf16x8*)(pnL + ks * 2048 + lane * 16);
            const bf16x8 f1 = *(const bf16x8*)(pnL + ks * 2048 + 1024 + lane * 16);
            a0 = __builtin_amdgcn_mfma_f32_16x16x32_bf16(f0, xf[ks], a0, 0, 0, 0);
            a1 = __builtin_amdgcn_mfma_f32_16x16x32_bf16(f1, xf[ks], a1, 0, 0, 0);
        }
        // p = exp(sim) (|sim|<=1 -> no max pass), mask, pack
        unsigned short pw[8];
        #pragma unroll
        for (int r = 0; r < 4; ++r) {
            const int n0 = c * 32 + g * 4 + r;
            const float p0 = (n0 < len) ? __expf(a0[r] * xinv) : 0.f;
            ssum += p0; pw[r] = f2bf(p0);
            const float p1 = (n0 + 16 < len) ? __expf(a1[r] * xinv) : 0.f;
            ssum += p1; pw[4 + r] = f2bf(p1);
        }
        pm[c][0] = (unsigned)pw[0] | ((unsigned)pw[1] << 16);
        pm[c][1] = (unsigned)pw[2] | ((unsigned)pw[3] << 16);
        pm[c][2] = (unsigned)pw[4] | ((unsigned)pw[5] << 16);
        pm[c][3] = (unsigned)pw[6] | ((unsigned)pw[7] << 16);
    }

    // ---- row sum (row w*16+lo lives on lanes lo, lo+16, lo+32, lo+48) ----
    ssum += __shfl_xor(ssum, 16);
    ssum += __shfl_xor(ssum, 32);
    const float sinv = 1.0f / ssum;

    // ================= E phase (W stores interleaved) =================
    // Queue audit (oldest->newest) before wait at iter c:
    //  c=0:[pe0,pe1,pe2]=12 -> vmcnt(8);  c=1:[pe1,pe2,pe3,W0]=14 -> vmcnt(10)
    //  2<=c<=13: 18 -> vmcnt(12);  c=14: 14 -> vmcnt(8);  c=15: 10 -> vmcnt(4)
    f32x4 e[16];
    #pragma unroll
    for (int i = 0; i < 16; ++i) e[i] = (f32x4){0.f, 0.f, 0.f, 0.f};

    float* Wrow = out + (size_t)BB * LL * DD
                + ((size_t)b * LL + l0 + w * 16 + lo) * (size_t)NN;

    #pragma unroll
    for (int c = 0; c < 16; ++c) {
        if      (c == 0) asm volatile("s_waitcnt vmcnt(8)"  ::: "memory");
        else if (c == 1) asm volatile("s_waitcnt vmcnt(10)" ::: "memory");
        else if (c <= 13) asm volatile("s_waitcnt vmcnt(12)" ::: "memory");
        else if (c == 14) asm volatile("s_waitcnt vmcnt(8)"  ::: "memory");
        else             asm volatile("s_waitcnt vmcnt(4)"  ::: "memory");
        __builtin_amdgcn_s_barrier();
        __builtin_amdgcn_sched_barrier(0);
        if (c < 13) {                          // issue pe(c+3) into buf (c+3)&3
            const char* src = peB + (c + 3) * 16384;
            char* dst = stg + ((c + 3) & 3) * 16384;
            #pragma unroll
            for (int q = 0; q < 4; ++q)
                GLL16(src + q * 4096 + tid * 16, dst + q * 4096 + tid * 16);
        }
        // W stores: full 128B line per row across the wave (2 stores/thread)
        float4 v0, v1;
        v0.x = bflo(pm[c][0]) * sinv; v0.y = bfhi(pm[c][0]) * sinv;
        v0.z = bflo(pm[c][1]) * sinv; v0.w = bfhi(pm[c][1]) * sinv;
        v1.x = bflo(pm[c][2]) * sinv; v1.y = bfhi(pm[c][2]) * sinv;
        v1.z = bflo(pm[c][3]) * sinv; v1.w = bfhi(pm[c][3]) * sinv;
        *(float4*)(Wrow + c * 32 + g * 4)      = v0;
        *(float4*)(Wrow + c * 32 + 16 + g * 4) = v1;

        // E += p-frag . pe
        union { unsigned u[4]; bf16x8 v; } pf;
        pf.u[0] = pm[c][0]; pf.u[1] = pm[c][1];
        pf.u[2] = pm[c][2]; pf.u[3] = pm[c][3];
        const char* peL = stg + (c & 3) * 16384;
        #pragma unroll
        for (int df = 0; df < 16; ++df) {      // contiguous 1KB wave reads
            const bf16x8 bf = *(const bf16x8*)(peL + df * 1024 + lane * 16);
            e[df] = __builtin_amdgcn_mfma_f32_16x16x32_bf16(pf.v, bf, e[df], 0, 0, 0);
        }
    }
    __syncthreads();                           // all ring readers done -> scratch ok

    // ---- E epilogue: per-wave transpose via own 16KB slab, float4 stores ----
    float t4[4];
    #pragma unroll
    for (int r = 0; r < 4; ++r) t4[r] = __shfl(sinv, g * 4 + r);
    char* scr = stg + w * 16384;               // stride 1056: writes 2-way, reads linear
    float* Eout = out + ((size_t)b * LL + l0 + w * 16) * DD;
    #pragma unroll
    for (int r = 0; r < 4; ++r) {
        #pragma unroll
        for (int df = 0; df < 16; ++df)
            *(float*)(scr + g * 1056 + df * 64 + lo * 4) = e[df][r] * t4[r];
        #pragma unroll
        for (int it = 0; it < 4; ++it) {
            const float4 t = *(const float4*)(scr + it * 1056 + lane * 16);
            *(float4*)(Eout + (size_t)(it * 4 + r) * DD + lane * 4) = t;
        }
    }
}

extern "C" void kernel_launch(void* const* d_in, const int* in_sizes, int n_in,
                              void* d_out, int out_size, void* d_ws, size_t ws_size,
                              hipStream_t stream) {
    const float* X    = (const float*)d_in[0];
    const float* P    = (const float*)d_in[1];
    const int*   lens = (const int*)d_in[2];
    float*       out  = (float*)d_out;

    // workspace: pnI (4MB) | peI (4MB)
    char* pnI = (char*)d_ws;
    char* peI = (char*)d_ws + 4194304;

    hipLaunchKernelGGL(cda_prep, dim3(BB * 16), dim3(512), 0, stream, P, pnI, peI);
    hipLaunchKernelGGL(cda_main, dim3(1024), dim3(256), 0, stream, X, pnI, peI, lens, out);
}